// Round 1
// baseline (40059.369 us; speedup 1.0000x reference)
//
#include <hip/hip_runtime.h>

#define B    64
#define T    512
#define H    600
#define G3   1800
#define IN0  300
#define NBLK 150    // 4 j-columns per block (150*4 = 600)
#define NTHR 256
#define TCH  16     // timesteps per gi chunk (chunk x-slice and gi stay L2-resident)
#define NCHUNK (T / TCH)   // 32
#define KPW  600    // LDS row stride (floats): 3*KPW % 32 == 8 -> the 4 jj rows'
                    // bases land on banks {0,8,16,24}; b128 reads are conflict-free.

// ---------------- ws layout (floats) ----------------
#define WI0_OFF 0
#define WI0_SZ  (IN0 * G3)                 // 540,000
#define WH_SZ   (H * G3)                   // 1,080,000
#define WH0_OFF (WI0_OFF + WI0_SZ)
#define WI1_OFF (WH0_OFF + WH_SZ)
#define WH1_OFF (WI1_OFF + WH_SZ)
#define BC0_OFF (WH1_OFF + WH_SZ)
#define BC1_OFF (BC0_OFF + H * 4)
#define HA_OFF  (BC1_OFF + H * 4)
#define HB_OFF  (HA_OFF + B * H)
#define GI_OFF  (HB_OFF + B * H)
#define GI_SZ   (TCH * B * H * 4)          // 2,457,600 (gi4: [tl][b][j][4])
#define BAR_OFF (GI_OFF + GI_SZ)           // 256 ints: flags[0..149], gen at [192]

// ---------------- distributed-flag grid barrier (plain launch, agent scope) ----
// Arrival: each block's thread0 release-stores its generation into its own flag
// (no RMW contention). Block 0's wave 0 scans the 150 flags in parallel and
// release-stores gen. Everyone else acquire-polls gen. Monotonic counts = ABA-safe.
__device__ __forceinline__ void grid_barrier(int* __restrict__ flags,
                                             int* __restrict__ gen, int& bno) {
    ++bno;
    __syncthreads();
    if (threadIdx.x == 0) {
        __hip_atomic_store(&flags[blockIdx.x], bno, __ATOMIC_RELEASE, __HIP_MEMORY_SCOPE_AGENT);
    }
    if (blockIdx.x == 0 && threadIdx.x < 64) {
        for (;;) {
            int ok = 1;
            for (int i = threadIdx.x; i < NBLK; i += 64) {
                if (__hip_atomic_load(&flags[i], __ATOMIC_ACQUIRE, __HIP_MEMORY_SCOPE_AGENT) < bno)
                    ok = 0;
            }
            if (__all(ok)) break;
            __builtin_amdgcn_s_sleep(1);
        }
        if (threadIdx.x == 0)
            __hip_atomic_store(gen, bno, __ATOMIC_RELEASE, __HIP_MEMORY_SCOPE_AGENT);
    }
    if (threadIdx.x == 0) {
        while (__hip_atomic_load(gen, __ATOMIC_ACQUIRE, __HIP_MEMORY_SCOPE_AGENT) < bno)
            __builtin_amdgcn_s_sleep(1);
    }
    __syncthreads();
}

__global__ void init_bar(int* bar) { if (threadIdx.x < 256) bar[threadIdx.x] = 0; }

// Pack W[(g*H+j)][k] -> dst[k][j*3+g]  (k-major, gate-interleaved columns)
__global__ void build_wp(const float* __restrict__ W, float* __restrict__ dst, int kdim) {
    int idx = blockIdx.x * blockDim.x + threadIdx.x;
    if (idx >= kdim * G3) return;
    int k = idx / G3;
    int c = idx - k * G3;
    int j = c / 3;
    int g = c - j * 3;
    dst[idx] = W[(size_t)(g * H + j) * kdim + k];
}

// BC[j] = (bih_r+bhh_r, bih_z+bhh_z, bih_n, bhh_n)
__global__ void build_bc(const float* __restrict__ bih0, const float* __restrict__ bhh0,
                         const float* __restrict__ bih1, const float* __restrict__ bhh1,
                         float* __restrict__ BC0, float* __restrict__ BC1) {
    int j = blockIdx.x * blockDim.x + threadIdx.x;
    if (j >= H) return;
    BC0[j * 4 + 0] = bih0[j] + bhh0[j];
    BC0[j * 4 + 1] = bih0[H + j] + bhh0[H + j];
    BC0[j * 4 + 2] = bih0[2 * H + j];
    BC0[j * 4 + 3] = bhh0[2 * H + j];
    BC1[j * 4 + 0] = bih1[j] + bhh1[j];
    BC1[j * 4 + 1] = bih1[H + j] + bhh1[H + j];
    BC1[j * 4 + 2] = bih1[2 * H + j];
    BC1[j * 4 + 3] = bhh1[2 * H + j];
}

// Dual-batch triple dot over N4 float4s: two global h streams (ping-pong
// double-buffered, CH float4 in flight each), shared LDS weight reads.
// Each weight float4 feeds 24 FMAs (2 batches x 3 gates) -> halves LDS traffic.
template<int N4, int CH>
__device__ __forceinline__ void dot3x2(const float4* __restrict__ a0,
                                       const float4* __restrict__ a1,
                                       const float* wr, const float* wz, const float* wn,
                                       float& sr0, float& sz0, float& sn0,
                                       float& sr1, float& sz1, float& sn1) {
    constexpr int NCH = N4 / CH;
    static_assert(N4 % CH == 0, "chunking");
    float4 A0[CH], A1[CH], B0[CH], B1[CH];
    #pragma unroll
    for (int i = 0; i < CH; ++i) { A0[i] = a0[i]; A1[i] = a1[i]; }
    #pragma unroll 1
    for (int c = 0; c < NCH; c += 2) {
        if (c + 1 < NCH) {
            const float4* p0 = a0 + (c + 1) * CH;
            const float4* p1 = a1 + (c + 1) * CH;
            #pragma unroll
            for (int i = 0; i < CH; ++i) { B0[i] = p0[i]; B1[i] = p1[i]; }
        }
        #pragma unroll
        for (int i = 0; i < CH; ++i) {
            const int k = (c * CH + i) * 4;
            const float4 wR = *(const float4*)(wr + k);
            const float4 wZ = *(const float4*)(wz + k);
            const float4 wN = *(const float4*)(wn + k);
            float4 a = A0[i];
            sr0 += a.x * wR.x + a.y * wR.y + a.z * wR.z + a.w * wR.w;
            sz0 += a.x * wZ.x + a.y * wZ.y + a.z * wZ.z + a.w * wZ.w;
            sn0 += a.x * wN.x + a.y * wN.y + a.z * wN.z + a.w * wN.w;
            a = A1[i];
            sr1 += a.x * wR.x + a.y * wR.y + a.z * wR.z + a.w * wR.w;
            sz1 += a.x * wZ.x + a.y * wZ.y + a.z * wZ.z + a.w * wZ.w;
            sn1 += a.x * wN.x + a.y * wN.y + a.z * wN.z + a.w * wN.w;
        }
        if (c + 1 < NCH) {
            if (c + 2 < NCH) {
                const float4* p0 = a0 + (c + 2) * CH;
                const float4* p1 = a1 + (c + 2) * CH;
                #pragma unroll
                for (int i = 0; i < CH; ++i) { A0[i] = p0[i]; A1[i] = p1[i]; }
            }
            #pragma unroll
            for (int i = 0; i < CH; ++i) {
                const int k = ((c + 1) * CH + i) * 4;
                const float4 wR = *(const float4*)(wr + k);
                const float4 wZ = *(const float4*)(wz + k);
                const float4 wN = *(const float4*)(wn + k);
                float4 a = B0[i];
                sr0 += a.x * wR.x + a.y * wR.y + a.z * wR.z + a.w * wR.w;
                sz0 += a.x * wZ.x + a.y * wZ.y + a.z * wZ.z + a.w * wZ.w;
                sn0 += a.x * wN.x + a.y * wN.y + a.z * wN.z + a.w * wN.w;
                a = B1[i];
                sr1 += a.x * wR.x + a.y * wR.y + a.z * wR.z + a.w * wR.w;
                sz1 += a.x * wZ.x + a.y * wZ.y + a.z * wZ.z + a.w * wZ.w;
                sn1 += a.x * wN.x + a.y * wN.y + a.z * wN.z + a.w * wN.w;
            }
        }
    }
}

// Input-GEMM inner: 8 consecutive t-rows of one batch vs this thread's 3 gate
// columns. Weights amortized 96 FMAs per LDS triple; x ping-pong double-buffered.
template<int KIN>
__device__ __forceinline__ void gemm8(const float* xb,
                                      const float* wr, const float* wz, const float* wn,
                                      float* aR, float* aZ, float* aN) {
    constexpr int N4 = KIN / 4;
    float4 X[8], Y[8];
    #pragma unroll
    for (int i = 0; i < 8; ++i) X[i] = *(const float4*)(xb + (size_t)i * KIN);
    #pragma unroll 1
    for (int c = 0; c < N4; c += 2) {
        if (c + 1 < N4) {
            #pragma unroll
            for (int i = 0; i < 8; ++i) Y[i] = *(const float4*)(xb + (size_t)i * KIN + (c + 1) * 4);
        }
        {
            const int k = c * 4;
            const float4 wR = *(const float4*)(wr + k);
            const float4 wZ = *(const float4*)(wz + k);
            const float4 wN = *(const float4*)(wn + k);
            #pragma unroll
            for (int i = 0; i < 8; ++i) {
                const float4 a = X[i];
                aR[i] += a.x * wR.x + a.y * wR.y + a.z * wR.z + a.w * wR.w;
                aZ[i] += a.x * wZ.x + a.y * wZ.y + a.z * wZ.z + a.w * wZ.w;
                aN[i] += a.x * wN.x + a.y * wN.y + a.z * wN.z + a.w * wN.w;
            }
        }
        if (c + 1 < N4) {
            if (c + 2 < N4) {
                #pragma unroll
                for (int i = 0; i < 8; ++i) X[i] = *(const float4*)(xb + (size_t)i * KIN + (c + 2) * 4);
            }
            const int k = (c + 1) * 4;
            const float4 wR = *(const float4*)(wr + k);
            const float4 wZ = *(const float4*)(wz + k);
            const float4 wN = *(const float4*)(wn + k);
            #pragma unroll
            for (int i = 0; i < 8; ++i) {
                const float4 a = Y[i];
                aR[i] += a.x * wR.x + a.y * wR.y + a.z * wR.z + a.w * wR.w;
                aZ[i] += a.x * wZ.x + a.y * wZ.y + a.z * wZ.z + a.w * wZ.w;
                aN[i] += a.x * wN.x + a.y * wN.y + a.z * wN.z + a.w * wN.w;
            }
        }
    }
}

// x and ret may alias (layer 1) -> both non-restrict.
template<int LAYER>
__device__ void gru_layer(const float* x, const float* __restrict__ hid,
                          const float* __restrict__ WIp, const float* __restrict__ WHp,
                          const float* __restrict__ BC,
                          float* __restrict__ hA, float* __restrict__ hB,
                          float* __restrict__ gi, float* ret, float* __restrict__ outh,
                          float* Wi, float* Wh, int* flags, int* gen, int& bno) {
    constexpr int KIN = LAYER ? H : IN0;
    const int tid = threadIdx.x;
    const int jj = tid & 3;
    const int j = blockIdx.x * 4 + jj;
    const int wcol0 = blockIdx.x * 12;

    // Stage this block's 12 W_ih columns and 12 W_hh columns into LDS (once/layer).
    for (int idx = tid; idx < 12 * KIN; idx += NTHR) {
        int k = idx / 12, c = idx - k * 12;
        Wi[c * KPW + k] = WIp[(size_t)k * G3 + wcol0 + c];
    }
    for (int idx = tid; idx < 12 * H; idx += NTHR) {
        int k = idx / 12, c = idx - k * 12;
        Wh[c * KPW + k] = WHp[(size_t)k * G3 + wcol0 + c];
    }
    hA[blockIdx.x * NTHR + tid] = hid[blockIdx.x * NTHR + tid];   // 150*256 == B*H
    grid_barrier(flags, gen, bno);   // covers LDS staging + hA init

    const float4 bc = *(const float4*)(BC + j * 4);
    const float* wrI = &Wi[(jj * 3 + 0) * KPW];
    const float* wzI = &Wi[(jj * 3 + 1) * KPW];
    const float* wnI = &Wi[(jj * 3 + 2) * KPW];
    const float* wrH = &Wh[(jj * 3 + 0) * KPW];
    const float* wzH = &Wh[(jj * 3 + 1) * KPW];
    const float* wnH = &Wh[(jj * 3 + 2) * KPW];

    const int bg = tid >> 2;           // GEMM phase: batch 0..63
    const int bp = tid >> 2;           // scan phase (tid<128): 0..31
    const int b0 = bp, b1 = bp + 32;
    float hv0 = 0.f, hv1 = 0.f;        // recurrent state lives in registers
    if (tid < 128) { hv0 = hid[b0 * H + j]; hv1 = hid[b1 * H + j]; }

    float* hc = hA;
    float* hn = hB;

    #pragma unroll 1
    for (int ch = 0; ch < NCHUNK; ++ch) {
        const int t0 = ch * TCH;

        // ---- gi GEMM phase: all 256 threads, batch bg, rows t0..t0+15 ----
        #pragma unroll 1
        for (int g = 0; g < TCH / 8; ++g) {
            float aR[8], aZ[8], aN[8];
            #pragma unroll
            for (int i = 0; i < 8; ++i) { aR[i] = 0.f; aZ[i] = 0.f; aN[i] = 0.f; }
            const float* xb = x + ((size_t)bg * T + t0 + g * 8) * KIN;
            gemm8<KIN>(xb, wrI, wzI, wnI, aR, aZ, aN);
            #pragma unroll
            for (int i = 0; i < 8; ++i) {
                float4 o;
                o.x = aR[i] + bc.x;   // r pre-activation + both r biases
                o.y = aZ[i] + bc.y;   // z pre-activation + both z biases
                o.z = aN[i] + bc.z;   // n x-part + bih_n
                o.w = bc.w;           // bhh_n (added inside r*(.) in scan)
                *(float4*)(gi + ((size_t)((g * 8 + i) * B + bg) * H + j) * 4) = o;
            }
        }
        // gi for (b, j) is written and read by the SAME block -> block barrier only.
        __syncthreads();

        // ---- scan: 16 sequential steps, 128 threads (4j x 32bp x 2 batches) ----
        #pragma unroll 1
        for (int tl = 0; tl < TCH; ++tl) {
            if (tid < 128) {
                const float4 g0 = *(const float4*)(gi + ((size_t)(tl * B + b0) * H + j) * 4);
                const float4 g1 = *(const float4*)(gi + ((size_t)(tl * B + b1) * H + j) * 4);
                float sr0 = 0.f, sz0 = 0.f, sn0 = 0.f, sr1 = 0.f, sz1 = 0.f, sn1 = 0.f;
                dot3x2<H / 4, 6>((const float4*)(hc + b0 * H), (const float4*)(hc + b1 * H),
                                 wrH, wzH, wnH, sr0, sz0, sn0, sr1, sz1, sn1);
                const int t = t0 + tl;
                float r0 = 1.f / (1.f + __expf(-(sr0 + g0.x)));
                float z0 = 1.f / (1.f + __expf(-(sz0 + g0.y)));
                float n0 = tanhf(g0.z + r0 * (sn0 + g0.w));
                hv0 = (1.f - z0) * n0 + z0 * hv0;
                hn[b0 * H + j] = hv0;
                ret[((size_t)b0 * T + t) * H + j] = hv0;
                float r1 = 1.f / (1.f + __expf(-(sr1 + g1.x)));
                float z1 = 1.f / (1.f + __expf(-(sz1 + g1.y)));
                float n1 = tanhf(g1.z + r1 * (sn1 + g1.w));
                hv1 = (1.f - z1) * n1 + z1 * hv1;
                hn[b1 * H + j] = hv1;
                ret[((size_t)b1 * T + t) * H + j] = hv1;
            }
            grid_barrier(flags, gen, bno);   // h all-to-all exchange
            float* tmp = hc; hc = hn; hn = tmp;
        }
    }
    if (tid < 128) { outh[b0 * H + j] = hv0; outh[b1 * H + j] = hv1; }
    grid_barrier(flags, gen, bno);   // ret complete before next layer's GEMM reads it
}

__global__ void __launch_bounds__(NTHR, 1) gru_main(
    const float* x0, const float* __restrict__ hid,
    const float* __restrict__ WI0, const float* __restrict__ WH0,
    const float* __restrict__ WI1, const float* __restrict__ WH1,
    const float* __restrict__ BC0, const float* __restrict__ BC1,
    float* __restrict__ hA, float* __restrict__ hB, float* __restrict__ gi,
    float* ret, float* __restrict__ outh, int* bar) {
    __shared__ __align__(16) float Wi[12 * KPW];   // 28,800 B
    __shared__ __align__(16) float Wh[12 * KPW];   // 28,800 B
    int* flags = bar;
    int* gen = bar + 192;
    int bno = 0;
    gru_layer<0>(x0,  hid,         WI0, WH0, BC0, hA, hB, gi, ret, outh,         Wi, Wh, flags, gen, bno);
    gru_layer<1>(ret, hid + B * H, WI1, WH1, BC1, hA, hB, gi, ret, outh + B * H, Wi, Wh, flags, gen, bno);
}

extern "C" void kernel_launch(void* const* d_in, const int* in_sizes, int n_in,
                              void* d_out, int out_size, void* d_ws, size_t ws_size,
                              hipStream_t stream) {
    const float* x0   = (const float*)d_in[0];
    const float* hid  = (const float*)d_in[1];
    const float* Wih0 = (const float*)d_in[2];
    const float* Whh0 = (const float*)d_in[3];
    const float* bih0 = (const float*)d_in[4];
    const float* bhh0 = (const float*)d_in[5];
    const float* Wih1 = (const float*)d_in[6];
    const float* Whh1 = (const float*)d_in[7];
    const float* bih1 = (const float*)d_in[8];
    const float* bhh1 = (const float*)d_in[9];

    float* ws  = (float*)d_ws;
    float* WI0 = ws + WI0_OFF;
    float* WH0 = ws + WH0_OFF;
    float* WI1 = ws + WI1_OFF;
    float* WH1 = ws + WH1_OFF;
    float* BC0 = ws + BC0_OFF;
    float* BC1 = ws + BC1_OFF;
    float* hA  = ws + HA_OFF;
    float* hB  = ws + HB_OFF;
    float* gi  = ws + GI_OFF;
    int*   bar = (int*)(ws + BAR_OFF);

    float* ret  = (float*)d_out;
    float* outh = ret + (size_t)B * T * H;

    build_wp<<<(IN0 * G3 + 255) / 256, 256, 0, stream>>>(Wih0, WI0, IN0);
    build_wp<<<(H * G3 + 255) / 256, 256, 0, stream>>>(Whh0, WH0, H);
    build_wp<<<(H * G3 + 255) / 256, 256, 0, stream>>>(Wih1, WI1, H);
    build_wp<<<(H * G3 + 255) / 256, 256, 0, stream>>>(Whh1, WH1, H);
    build_bc<<<(H + 255) / 256, 256, 0, stream>>>(bih0, bhh0, bih1, bhh1, BC0, BC1);
    init_bar<<<1, 256, 0, stream>>>(bar);

    gru_main<<<dim3(NBLK), dim3(NTHR), 0, stream>>>(
        x0, hid, WI0, WH0, WI1, WH1, BC0, BC1, hA, hB, gi, ret, outh, bar);
}

// Round 2
// 28284.451 us; speedup vs baseline: 1.4163x; 1.4163x over previous
//
#include <hip/hip_runtime.h>

#define B    64
#define T    512
#define H    600
#define G3   1800
#define IN0  300
#define NBLK 150    // 4 j-columns per block (150*4 = 600)
#define NTHR 512    // (b:64) x (jj:4) x (kh:2) -> 8 waves/CU, 1 block/CU
#define TCH  16     // timesteps per gi chunk
#define NCHUNK (T / TCH)   // 32
#define KPW  600    // LDS row stride (floats). Scan reads: 8 unique bases/wave
                    // (jj x kh); row stride 3*600 -> +8 banks, kh -> +12 banks:
                    // bases hit banks {0,8,16,24,12,20,28,4} -> each b128 quad
                    // covers a disjoint 4-bank group; all 32 banks, conflict-free.

// ---------------- ws layout (floats) ----------------
#define WI0_OFF 0
#define WI0_SZ  (IN0 * G3)                 // 540,000
#define WH_SZ   (H * G3)                   // 1,080,000
#define WH0_OFF (WI0_OFF + WI0_SZ)
#define WI1_OFF (WH0_OFF + WH_SZ)
#define WH1_OFF (WI1_OFF + WH_SZ)
#define BC0_OFF (WH1_OFF + WH_SZ)
#define BC1_OFF (BC0_OFF + H * 4)
#define HA_OFF  (BC1_OFF + H * 4)
#define HB_OFF  (HA_OFF + B * H)
#define GI_OFF  (HB_OFF + B * H)
#define GI_SZ   (TCH * B * H * 4)          // gi4: [tl][b][j][4]
#define BAR_OFF (GI_OFF + GI_SZ)           // 256 ints: flags[0..149], gen at [192]

// ---------------- distributed-flag grid barrier (plain launch, agent scope) ----
__device__ __forceinline__ void grid_barrier(int* __restrict__ flags,
                                             int* __restrict__ gen, int& bno) {
    ++bno;
    __syncthreads();
    if (threadIdx.x == 0) {
        __hip_atomic_store(&flags[blockIdx.x], bno, __ATOMIC_RELEASE, __HIP_MEMORY_SCOPE_AGENT);
    }
    if (blockIdx.x == 0 && threadIdx.x < 64) {
        for (;;) {
            int ok = 1;
            for (int i = threadIdx.x; i < NBLK; i += 64) {
                if (__hip_atomic_load(&flags[i], __ATOMIC_ACQUIRE, __HIP_MEMORY_SCOPE_AGENT) < bno)
                    ok = 0;
            }
            if (__all(ok)) break;
            __builtin_amdgcn_s_sleep(1);
        }
        if (threadIdx.x == 0)
            __hip_atomic_store(gen, bno, __ATOMIC_RELEASE, __HIP_MEMORY_SCOPE_AGENT);
    }
    if (threadIdx.x == 0) {
        while (__hip_atomic_load(gen, __ATOMIC_ACQUIRE, __HIP_MEMORY_SCOPE_AGENT) < bno)
            __builtin_amdgcn_s_sleep(1);
    }
    __syncthreads();
}

__global__ void init_bar(int* bar) { if (threadIdx.x < 256) bar[threadIdx.x] = 0; }

// Pack W[(g*H+j)][k] -> dst[k][j*3+g]  (k-major, gate-interleaved columns)
__global__ void build_wp(const float* __restrict__ W, float* __restrict__ dst, int kdim) {
    int idx = blockIdx.x * blockDim.x + threadIdx.x;
    if (idx >= kdim * G3) return;
    int k = idx / G3;
    int c = idx - k * G3;
    int j = c / 3;
    int g = c - j * 3;
    dst[idx] = W[(size_t)(g * H + j) * kdim + k];
}

// BC[j] = (bih_r+bhh_r, bih_z+bhh_z, bih_n, bhh_n)
__global__ void build_bc(const float* __restrict__ bih0, const float* __restrict__ bhh0,
                         const float* __restrict__ bih1, const float* __restrict__ bhh1,
                         float* __restrict__ BC0, float* __restrict__ BC1) {
    int j = blockIdx.x * blockDim.x + threadIdx.x;
    if (j >= H) return;
    BC0[j * 4 + 0] = bih0[j] + bhh0[j];
    BC0[j * 4 + 1] = bih0[H + j] + bhh0[H + j];
    BC0[j * 4 + 2] = bih0[2 * H + j];
    BC0[j * 4 + 3] = bhh0[2 * H + j];
    BC1[j * 4 + 0] = bih1[j] + bhh1[j];
    BC1[j * 4 + 1] = bih1[H + j] + bhh1[H + j];
    BC1[j * 4 + 2] = bih1[2 * H + j];
    BC1[j * 4 + 3] = bhh1[2 * H + j];
}

// Triple fp32 dot over N4 float4s. a: global, double-buffered register pipeline
// (CH float4 in flight). w: LDS float4 reads. #pragma unroll 1 keeps ONE copy
// of the ping-pong body (bounded register pressure). Handles odd NCH.
template<int N4, int CH>
__device__ __forceinline__ void dot3f(const float4* __restrict__ ap,
                                      const float* __restrict__ wr,
                                      const float* __restrict__ wz,
                                      const float* __restrict__ wn,
                                      float& sr, float& sz, float& sn) {
    constexpr int NCH = N4 / CH;
    static_assert(N4 % CH == 0, "chunking");
    float4 A[CH], Bf[CH];
    #pragma unroll
    for (int i = 0; i < CH; ++i) A[i] = ap[i];
    #pragma unroll 1
    for (int c = 0; c < NCH; c += 2) {
        if (c + 1 < NCH) {
            const float4* p = ap + (c + 1) * CH;
            #pragma unroll
            for (int i = 0; i < CH; ++i) Bf[i] = p[i];
        }
        #pragma unroll
        for (int i = 0; i < CH; ++i) {
            const int k = (c * CH + i) * 4;
            float4 a = A[i];
            const float4 wR = *(const float4*)(wr + k);
            const float4 wZ = *(const float4*)(wz + k);
            const float4 wN = *(const float4*)(wn + k);
            sr += a.x * wR.x + a.y * wR.y + a.z * wR.z + a.w * wR.w;
            sz += a.x * wZ.x + a.y * wZ.y + a.z * wZ.z + a.w * wZ.w;
            sn += a.x * wN.x + a.y * wN.y + a.z * wN.z + a.w * wN.w;
        }
        if (c + 1 < NCH) {
            if (c + 2 < NCH) {
                const float4* p = ap + (c + 2) * CH;
                #pragma unroll
                for (int i = 0; i < CH; ++i) A[i] = p[i];
            }
            #pragma unroll
            for (int i = 0; i < CH; ++i) {
                const int k = ((c + 1) * CH + i) * 4;
                float4 a = Bf[i];
                const float4 wR = *(const float4*)(wr + k);
                const float4 wZ = *(const float4*)(wz + k);
                const float4 wN = *(const float4*)(wn + k);
                sr += a.x * wR.x + a.y * wR.y + a.z * wR.z + a.w * wR.w;
                sz += a.x * wZ.x + a.y * wZ.y + a.z * wZ.z + a.w * wZ.w;
                sn += a.x * wN.x + a.y * wN.y + a.z * wN.z + a.w * wN.w;
            }
        }
    }
}

// Input-GEMM inner: 8 consecutive t-rows of one batch vs this thread's 3 gate
// columns. Weight LDS triple amortized over 96 FMAs; x ping-pong double-buffered.
template<int KIN>
__device__ __forceinline__ void gemm8(const float* xb,
                                      const float* wr, const float* wz, const float* wn,
                                      float* aR, float* aZ, float* aN) {
    constexpr int N4 = KIN / 4;
    float4 X[8], Y[8];
    #pragma unroll
    for (int i = 0; i < 8; ++i) X[i] = *(const float4*)(xb + (size_t)i * KIN);
    #pragma unroll 1
    for (int c = 0; c < N4; c += 2) {
        if (c + 1 < N4) {
            #pragma unroll
            for (int i = 0; i < 8; ++i) Y[i] = *(const float4*)(xb + (size_t)i * KIN + (c + 1) * 4);
        }
        {
            const int k = c * 4;
            const float4 wR = *(const float4*)(wr + k);
            const float4 wZ = *(const float4*)(wz + k);
            const float4 wN = *(const float4*)(wn + k);
            #pragma unroll
            for (int i = 0; i < 8; ++i) {
                const float4 a = X[i];
                aR[i] += a.x * wR.x + a.y * wR.y + a.z * wR.z + a.w * wR.w;
                aZ[i] += a.x * wZ.x + a.y * wZ.y + a.z * wZ.z + a.w * wZ.w;
                aN[i] += a.x * wN.x + a.y * wN.y + a.z * wN.z + a.w * wN.w;
            }
        }
        if (c + 1 < N4) {
            if (c + 2 < N4) {
                #pragma unroll
                for (int i = 0; i < 8; ++i) X[i] = *(const float4*)(xb + (size_t)i * KIN + (c + 2) * 4);
            }
            const int k = (c + 1) * 4;
            const float4 wR = *(const float4*)(wr + k);
            const float4 wZ = *(const float4*)(wz + k);
            const float4 wN = *(const float4*)(wn + k);
            #pragma unroll
            for (int i = 0; i < 8; ++i) {
                const float4 a = Y[i];
                aR[i] += a.x * wR.x + a.y * wR.y + a.z * wR.z + a.w * wR.w;
                aZ[i] += a.x * wZ.x + a.y * wZ.y + a.z * wZ.z + a.w * wZ.w;
                aN[i] += a.x * wN.x + a.y * wN.y + a.z * wN.z + a.w * wN.w;
            }
        }
    }
}

// x and ret may alias (layer 1) -> both non-restrict.
template<int LAYER>
__device__ void gru_layer(const float* x, const float* __restrict__ hid,
                          const float* __restrict__ WIp, const float* __restrict__ WHp,
                          const float* __restrict__ BC,
                          float* __restrict__ hA, float* __restrict__ hB,
                          float* __restrict__ gi, float* ret, float* __restrict__ outh,
                          float* Wi, float* Wh, int* flags, int* gen, int& bno) {
    constexpr int KIN = LAYER ? H : IN0;
    const int tid = threadIdx.x;
    const int jj = tid & 3;            // j column within block
    const int kh = (tid >> 2) & 1;     // K-half (scan) / t-row octet (GEMM); lane bit 2
    const int b  = tid >> 3;           // batch 0..63 (both phases)
    const int j  = blockIdx.x * 4 + jj;
    const int wcol0 = blockIdx.x * 12;

    // Stage this block's 12 W_ih and 12 W_hh gate-columns into LDS (once/layer).
    for (int idx = tid; idx < 12 * KIN; idx += NTHR) {
        int k = idx / 12, c = idx - k * 12;
        Wi[c * KPW + k] = WIp[(size_t)k * G3 + wcol0 + c];
    }
    for (int idx = tid; idx < 12 * H; idx += NTHR) {
        int k = idx / 12, c = idx - k * 12;
        Wh[c * KPW + k] = WHp[(size_t)k * G3 + wcol0 + c];
    }
    {
        int g = blockIdx.x * NTHR + tid;
        if (g < B * H) hA[g] = hid[g];
    }
    grid_barrier(flags, gen, bno);   // covers LDS staging + hA init

    const float4 bc = *(const float4*)(BC + j * 4);
    const float* wrI = &Wi[(jj * 3 + 0) * KPW];
    const float* wzI = &Wi[(jj * 3 + 1) * KPW];
    const float* wnI = &Wi[(jj * 3 + 2) * KPW];
    const float* wrH = &Wh[(jj * 3 + 0) * KPW] + kh * (H / 2);
    const float* wzH = &Wh[(jj * 3 + 1) * KPW] + kh * (H / 2);
    const float* wnH = &Wh[(jj * 3 + 2) * KPW] + kh * (H / 2);

    float hv = hid[b * H + j];         // recurrent state (maintained by kh=0 lanes)

    float* hc = hA;
    float* hn = hB;

    #pragma unroll 1
    for (int ch = 0; ch < NCHUNK; ++ch) {
        const int t0 = ch * TCH;

        // ---- gi GEMM phase: all 512 threads; batch b, col j, rows t0+kh*8.. ----
        {
            float aR[8], aZ[8], aN[8];
            #pragma unroll
            for (int i = 0; i < 8; ++i) { aR[i] = 0.f; aZ[i] = 0.f; aN[i] = 0.f; }
            const float* xb = x + ((size_t)b * T + t0 + kh * 8) * KIN;
            gemm8<KIN>(xb, wrI, wzI, wnI, aR, aZ, aN);
            #pragma unroll
            for (int i = 0; i < 8; ++i) {
                float4 o;
                o.x = aR[i] + bc.x;   // r pre-activation + both r biases
                o.y = aZ[i] + bc.y;   // z pre-activation + both z biases
                o.z = aN[i] + bc.z;   // n x-part + bih_n
                o.w = bc.w;           // bhh_n (added inside r*(.) in scan)
                *(float4*)(gi + ((size_t)((kh * 8 + i) * B + b) * H + j) * 4) = o;
            }
        }
        // gi for (b, j) written and read by the SAME block -> block barrier only.
        __syncthreads();

        // ---- scan: 16 sequential steps; every thread does a K-half dot ----
        #pragma unroll 1
        for (int tl = 0; tl < TCH; ++tl) {
            const float4 g4 = *(const float4*)(gi + ((size_t)(tl * B + b) * H + j) * 4);
            float sr = 0.f, sz = 0.f, sn = 0.f;
            dot3f<H / 8, 15>((const float4*)(hc + b * H + kh * (H / 2)),
                             wrH, wzH, wnH, sr, sz, sn);
            // combine K-halves: partner is lane^4 (kh is lane bit 2)
            sr += __shfl_xor(sr, 4);
            sz += __shfl_xor(sz, 4);
            sn += __shfl_xor(sn, 4);
            if (kh == 0) {
                float r = 1.f / (1.f + __expf(-(sr + g4.x)));
                float z = 1.f / (1.f + __expf(-(sz + g4.y)));
                float n = tanhf(g4.z + r * (sn + g4.w));
                hv = (1.f - z) * n + z * hv;
                hn[b * H + j] = hv;
                ret[((size_t)b * T + (t0 + tl)) * H + j] = hv;
            }
            grid_barrier(flags, gen, bno);   // h all-to-all exchange
            float* tmp = hc; hc = hn; hn = tmp;
        }
    }
    if (kh == 0) outh[b * H + j] = hv;
    grid_barrier(flags, gen, bno);   // ret complete before next layer's GEMM reads it
}

__global__ void __launch_bounds__(NTHR, 2) gru_main(
    const float* x0, const float* __restrict__ hid,
    const float* __restrict__ WI0, const float* __restrict__ WH0,
    const float* __restrict__ WI1, const float* __restrict__ WH1,
    const float* __restrict__ BC0, const float* __restrict__ BC1,
    float* __restrict__ hA, float* __restrict__ hB, float* __restrict__ gi,
    float* ret, float* __restrict__ outh, int* bar) {
    __shared__ __align__(16) float Wi[12 * KPW];   // 28,800 B
    __shared__ __align__(16) float Wh[12 * KPW];   // 28,800 B
    int* flags = bar;
    int* gen = bar + 192;
    int bno = 0;
    gru_layer<0>(x0,  hid,         WI0, WH0, BC0, hA, hB, gi, ret, outh,         Wi, Wh, flags, gen, bno);
    gru_layer<1>(ret, hid + B * H, WI1, WH1, BC1, hA, hB, gi, ret, outh + B * H, Wi, Wh, flags, gen, bno);
}

extern "C" void kernel_launch(void* const* d_in, const int* in_sizes, int n_in,
                              void* d_out, int out_size, void* d_ws, size_t ws_size,
                              hipStream_t stream) {
    const float* x0   = (const float*)d_in[0];
    const float* hid  = (const float*)d_in[1];
    const float* Wih0 = (const float*)d_in[2];
    const float* Whh0 = (const float*)d_in[3];
    const float* bih0 = (const float*)d_in[4];
    const float* bhh0 = (const float*)d_in[5];
    const float* Wih1 = (const float*)d_in[6];
    const float* Whh1 = (const float*)d_in[7];
    const float* bih1 = (const float*)d_in[8];
    const float* bhh1 = (const float*)d_in[9];

    float* ws  = (float*)d_ws;
    float* WI0 = ws + WI0_OFF;
    float* WH0 = ws + WH0_OFF;
    float* WI1 = ws + WI1_OFF;
    float* WH1 = ws + WH1_OFF;
    float* BC0 = ws + BC0_OFF;
    float* BC1 = ws + BC1_OFF;
    float* hA  = ws + HA_OFF;
    float* hB  = ws + HB_OFF;
    float* gi  = ws + GI_OFF;
    int*   bar = (int*)(ws + BAR_OFF);

    float* ret  = (float*)d_out;
    float* outh = ret + (size_t)B * T * H;

    build_wp<<<(IN0 * G3 + 255) / 256, 256, 0, stream>>>(Wih0, WI0, IN0);
    build_wp<<<(H * G3 + 255) / 256, 256, 0, stream>>>(Whh0, WH0, H);
    build_wp<<<(H * G3 + 255) / 256, 256, 0, stream>>>(Wih1, WI1, H);
    build_wp<<<(H * G3 + 255) / 256, 256, 0, stream>>>(Whh1, WH1, H);
    build_bc<<<(H + 255) / 256, 256, 0, stream>>>(bih0, bhh0, bih1, bhh1, BC0, BC1);
    init_bar<<<1, 256, 0, stream>>>(bar);

    gru_main<<<dim3(NBLK), dim3(NTHR), 0, stream>>>(
        x0, hid, WI0, WH0, WI1, WH1, BC0, BC1, hA, hB, gi, ret, outh, bar);
}

// Round 3
// 24072.826 us; speedup vs baseline: 1.6641x; 1.1750x over previous
//
#include <hip/hip_runtime.h>

#define B    64
#define T    512
#define H    600
#define G3   1800
#define IN0  300
#define NBLK 150    // 4 j-columns per block (150*4 = 600)
#define NTHR 512    // (b:64) x (jj:4) x (kh:2) -> 8 waves/CU, 1 block/CU
#define TCH  16     // timesteps per gi chunk
#define NCHUNK (T / TCH)   // 32
#define KPW  600    // LDS row stride (floats). Scan reads: 8 unique bases/wave
                    // (jj x kh); bases hit banks {0,8,16,24,12,20,28,4} -> each
                    // b128 quad covers a disjoint 4-bank group; conflict-free.

// ---------------- ws layout (floats) ----------------
#define WI0_OFF 0
#define WI0_SZ  (IN0 * G3)                 // 540,000
#define WH_SZ   (H * G3)                   // 1,080,000
#define WH0_OFF (WI0_OFF + WI0_SZ)
#define WI1_OFF (WH0_OFF + WH_SZ)
#define WH1_OFF (WI1_OFF + WH_SZ)
#define BC0_OFF (WH1_OFF + WH_SZ)
#define BC1_OFF (BC0_OFF + H * 4)
#define HA_OFF  (BC1_OFF + H * 4)
#define HB_OFF  (HA_OFF + B * H)
#define GI_OFF  (HB_OFF + B * H)
#define GI_SZ   (TCH * B * H * 4)          // gi4: [tl][b][j][4]
#define BAR_OFF (GI_OFF + GI_SZ)           // 256 ints: cnt at [0], gen[s] at [16+s*16]

// ---------------- grid barrier v3: RMW-poll, single-acquire ----------------
// Rationale (round-2 post-mortem): ACQUIRE loads at agent scope emit an L2
// invalidate EVERY poll iteration -> 150 blocks continuously thrash their
// XCD's L2 while waiting. Fix: poll with atomic fetch_add(p,0) (executes at
// L3, always fresh, NO cache invalidation), then do exactly ONE acquire load
// per step per block to invalidate stale L1/L2 before reading remote h.
// Arrival is a RELEASE fetch_add on a monotone counter (target bno*NBLK,
// ABA-free); completion is broadcast via 8 sharded gen lines (64B apart) so
// ~19 pollers share each address.
__device__ __forceinline__ void grid_barrier(int* __restrict__ cnt,
                                             int* __restrict__ gen, int& bno) {
    ++bno;
    __syncthreads();
    if (threadIdx.x == 0) {
        __hip_atomic_fetch_add(cnt, 1, __ATOMIC_RELEASE, __HIP_MEMORY_SCOPE_AGENT);
        if (blockIdx.x == 0) {
            const int tgt = bno * NBLK;
            while (__hip_atomic_fetch_add(cnt, 0, __ATOMIC_RELAXED, __HIP_MEMORY_SCOPE_AGENT) < tgt)
                __builtin_amdgcn_s_sleep(1);
            #pragma unroll
            for (int s = 0; s < 8; ++s)
                __hip_atomic_store(&gen[s * 16], bno, __ATOMIC_RELEASE, __HIP_MEMORY_SCOPE_AGENT);
        } else {
            int* g = &gen[(blockIdx.x & 7) * 16];
            while (__hip_atomic_fetch_add(g, 0, __ATOMIC_RELAXED, __HIP_MEMORY_SCOPE_AGENT) < bno)
                __builtin_amdgcn_s_sleep(1);
        }
        // the ONE cache-invalidating acquire for this step
        (void)__hip_atomic_load(cnt, __ATOMIC_ACQUIRE, __HIP_MEMORY_SCOPE_AGENT);
    }
    __syncthreads();
}

__global__ void init_bar(int* bar) { if (threadIdx.x < 256) bar[threadIdx.x] = 0; }

// Pack W[(g*H+j)][k] -> dst[k][j*3+g]  (k-major, gate-interleaved columns)
__global__ void build_wp(const float* __restrict__ W, float* __restrict__ dst, int kdim) {
    int idx = blockIdx.x * blockDim.x + threadIdx.x;
    if (idx >= kdim * G3) return;
    int k = idx / G3;
    int c = idx - k * G3;
    int j = c / 3;
    int g = c - j * 3;
    dst[idx] = W[(size_t)(g * H + j) * kdim + k];
}

// BC[j] = (bih_r+bhh_r, bih_z+bhh_z, bih_n, bhh_n)
__global__ void build_bc(const float* __restrict__ bih0, const float* __restrict__ bhh0,
                         const float* __restrict__ bih1, const float* __restrict__ bhh1,
                         float* __restrict__ BC0, float* __restrict__ BC1) {
    int j = blockIdx.x * blockDim.x + threadIdx.x;
    if (j >= H) return;
    BC0[j * 4 + 0] = bih0[j] + bhh0[j];
    BC0[j * 4 + 1] = bih0[H + j] + bhh0[H + j];
    BC0[j * 4 + 2] = bih0[2 * H + j];
    BC0[j * 4 + 3] = bhh0[2 * H + j];
    BC1[j * 4 + 0] = bih1[j] + bhh1[j];
    BC1[j * 4 + 1] = bih1[H + j] + bhh1[H + j];
    BC1[j * 4 + 2] = bih1[2 * H + j];
    BC1[j * 4 + 3] = bhh1[2 * H + j];
}

// Triple fp32 dot over N4 float4s. a: global, double-buffered register pipeline
// (CH float4 in flight). w: LDS float4 reads.
template<int N4, int CH>
__device__ __forceinline__ void dot3f(const float4* __restrict__ ap,
                                      const float* __restrict__ wr,
                                      const float* __restrict__ wz,
                                      const float* __restrict__ wn,
                                      float& sr, float& sz, float& sn) {
    constexpr int NCH = N4 / CH;
    static_assert(N4 % CH == 0, "chunking");
    float4 A[CH], Bf[CH];
    #pragma unroll
    for (int i = 0; i < CH; ++i) A[i] = ap[i];
    #pragma unroll 1
    for (int c = 0; c < NCH; c += 2) {
        if (c + 1 < NCH) {
            const float4* p = ap + (c + 1) * CH;
            #pragma unroll
            for (int i = 0; i < CH; ++i) Bf[i] = p[i];
        }
        #pragma unroll
        for (int i = 0; i < CH; ++i) {
            const int k = (c * CH + i) * 4;
            float4 a = A[i];
            const float4 wR = *(const float4*)(wr + k);
            const float4 wZ = *(const float4*)(wz + k);
            const float4 wN = *(const float4*)(wn + k);
            sr += a.x * wR.x + a.y * wR.y + a.z * wR.z + a.w * wR.w;
            sz += a.x * wZ.x + a.y * wZ.y + a.z * wZ.z + a.w * wZ.w;
            sn += a.x * wN.x + a.y * wN.y + a.z * wN.z + a.w * wN.w;
        }
        if (c + 1 < NCH) {
            if (c + 2 < NCH) {
                const float4* p = ap + (c + 2) * CH;
                #pragma unroll
                for (int i = 0; i < CH; ++i) A[i] = p[i];
            }
            #pragma unroll
            for (int i = 0; i < CH; ++i) {
                const int k = ((c + 1) * CH + i) * 4;
                float4 a = Bf[i];
                const float4 wR = *(const float4*)(wr + k);
                const float4 wZ = *(const float4*)(wz + k);
                const float4 wN = *(const float4*)(wn + k);
                sr += a.x * wR.x + a.y * wR.y + a.z * wR.z + a.w * wR.w;
                sz += a.x * wZ.x + a.y * wZ.y + a.z * wZ.z + a.w * wZ.w;
                sn += a.x * wN.x + a.y * wN.y + a.z * wN.z + a.w * wN.w;
            }
        }
    }
}

// Input-GEMM inner: 8 consecutive t-rows of one batch vs this thread's 3 gate
// columns. Weight LDS triple amortized over 96 FMAs; x ping-pong double-buffered.
template<int KIN>
__device__ __forceinline__ void gemm8(const float* xb,
                                      const float* wr, const float* wz, const float* wn,
                                      float* aR, float* aZ, float* aN) {
    constexpr int N4 = KIN / 4;
    float4 X[8], Y[8];
    #pragma unroll
    for (int i = 0; i < 8; ++i) X[i] = *(const float4*)(xb + (size_t)i * KIN);
    #pragma unroll 1
    for (int c = 0; c < N4; c += 2) {
        if (c + 1 < N4) {
            #pragma unroll
            for (int i = 0; i < 8; ++i) Y[i] = *(const float4*)(xb + (size_t)i * KIN + (c + 1) * 4);
        }
        {
            const int k = c * 4;
            const float4 wR = *(const float4*)(wr + k);
            const float4 wZ = *(const float4*)(wz + k);
            const float4 wN = *(const float4*)(wn + k);
            #pragma unroll
            for (int i = 0; i < 8; ++i) {
                const float4 a = X[i];
                aR[i] += a.x * wR.x + a.y * wR.y + a.z * wR.z + a.w * wR.w;
                aZ[i] += a.x * wZ.x + a.y * wZ.y + a.z * wZ.z + a.w * wZ.w;
                aN[i] += a.x * wN.x + a.y * wN.y + a.z * wN.z + a.w * wN.w;
            }
        }
        if (c + 1 < N4) {
            if (c + 2 < N4) {
                #pragma unroll
                for (int i = 0; i < 8; ++i) X[i] = *(const float4*)(xb + (size_t)i * KIN + (c + 2) * 4);
            }
            const int k = (c + 1) * 4;
            const float4 wR = *(const float4*)(wr + k);
            const float4 wZ = *(const float4*)(wz + k);
            const float4 wN = *(const float4*)(wn + k);
            #pragma unroll
            for (int i = 0; i < 8; ++i) {
                const float4 a = Y[i];
                aR[i] += a.x * wR.x + a.y * wR.y + a.z * wR.z + a.w * wR.w;
                aZ[i] += a.x * wZ.x + a.y * wZ.y + a.z * wZ.z + a.w * wZ.w;
                aN[i] += a.x * wN.x + a.y * wN.y + a.z * wN.z + a.w * wN.w;
            }
        }
    }
}

// x and ret may alias (layer 1) -> both non-restrict.
template<int LAYER>
__device__ void gru_layer(const float* x, const float* __restrict__ hid,
                          const float* __restrict__ WIp, const float* __restrict__ WHp,
                          const float* __restrict__ BC,
                          float* __restrict__ hA, float* __restrict__ hB,
                          float* __restrict__ gi, float* ret, float* __restrict__ outh,
                          float* Wi, float* Wh, int* cnt, int* gen, int& bno) {
    constexpr int KIN = LAYER ? H : IN0;
    const int tid = threadIdx.x;
    const int jj = tid & 3;            // j column within block
    const int kh = (tid >> 2) & 1;     // K-half (scan) / t-row octet (GEMM)
    const int b  = tid >> 3;           // batch 0..63 (both phases)
    const int j  = blockIdx.x * 4 + jj;
    const int wcol0 = blockIdx.x * 12;

    // Stage this block's 12 W_ih and 12 W_hh gate-columns into LDS (once/layer).
    for (int idx = tid; idx < 12 * KIN; idx += NTHR) {
        int k = idx / 12, c = idx - k * 12;
        Wi[c * KPW + k] = WIp[(size_t)k * G3 + wcol0 + c];
    }
    for (int idx = tid; idx < 12 * H; idx += NTHR) {
        int k = idx / 12, c = idx - k * 12;
        Wh[c * KPW + k] = WHp[(size_t)k * G3 + wcol0 + c];
    }
    {
        int g = blockIdx.x * NTHR + tid;
        if (g < B * H) __builtin_nontemporal_store(hid[g], &hA[g]);  // write-around L2
    }
    grid_barrier(cnt, gen, bno);   // covers LDS staging + hA init

    const float4 bc = *(const float4*)(BC + j * 4);
    const float* wrI = &Wi[(jj * 3 + 0) * KPW];
    const float* wzI = &Wi[(jj * 3 + 1) * KPW];
    const float* wnI = &Wi[(jj * 3 + 2) * KPW];
    const float* wrH = &Wh[(jj * 3 + 0) * KPW] + kh * (H / 2);
    const float* wzH = &Wh[(jj * 3 + 1) * KPW] + kh * (H / 2);
    const float* wnH = &Wh[(jj * 3 + 2) * KPW] + kh * (H / 2);

    float hv = hid[b * H + j];         // recurrent state (maintained by kh=0 lanes)

    float* hc = hA;
    float* hn = hB;

    #pragma unroll 1
    for (int ch = 0; ch < NCHUNK; ++ch) {
        const int t0 = ch * TCH;

        // ---- gi GEMM phase: all 512 threads; batch b, col j, rows t0+kh*8.. ----
        {
            float aR[8], aZ[8], aN[8];
            #pragma unroll
            for (int i = 0; i < 8; ++i) { aR[i] = 0.f; aZ[i] = 0.f; aN[i] = 0.f; }
            const float* xb = x + ((size_t)b * T + t0 + kh * 8) * KIN;
            gemm8<KIN>(xb, wrI, wzI, wnI, aR, aZ, aN);
            #pragma unroll
            for (int i = 0; i < 8; ++i) {
                float4 o;
                o.x = aR[i] + bc.x;   // r pre-activation + both r biases
                o.y = aZ[i] + bc.y;   // z pre-activation + both z biases
                o.z = aN[i] + bc.z;   // n x-part + bih_n
                o.w = bc.w;           // bhh_n (added inside r*(.) in scan)
                *(float4*)(gi + ((size_t)((kh * 8 + i) * B + b) * H + j) * 4) = o;
            }
        }
        // gi for (b, j) written and read by the SAME block -> block barrier only.
        __syncthreads();

        // ---- scan: 16 sequential steps; every thread does a K-half dot ----
        #pragma unroll 1
        for (int tl = 0; tl < TCH; ++tl) {
            const float4 g4 = *(const float4*)(gi + ((size_t)(tl * B + b) * H + j) * 4);
            float sr = 0.f, sz = 0.f, sn = 0.f;
            dot3f<H / 8, 15>((const float4*)(hc + b * H + kh * (H / 2)),
                             wrH, wzH, wnH, sr, sz, sn);
            // combine K-halves: partner is lane^4 (kh is lane bit 2)
            sr += __shfl_xor(sr, 4);
            sz += __shfl_xor(sz, 4);
            sn += __shfl_xor(sn, 4);
            if (kh == 0) {
                float r = 1.f / (1.f + __expf(-(sr + g4.x)));
                float z = 1.f / (1.f + __expf(-(sz + g4.y)));
                float n = tanhf(g4.z + r * (sn + g4.w));
                hv = (1.f - z) * n + z * hv;
                // non-temporal: write around L2 so the release-writeback is cheap
                __builtin_nontemporal_store(hv, &hn[b * H + j]);
                __builtin_nontemporal_store(hv, &ret[((size_t)b * T + (t0 + tl)) * H + j]);
            }
            grid_barrier(cnt, gen, bno);   // h all-to-all exchange
            float* tmp = hc; hc = hn; hn = tmp;
        }
    }
    if (kh == 0) __builtin_nontemporal_store(hv, &outh[b * H + j]);
    grid_barrier(cnt, gen, bno);   // ret complete before next layer's GEMM reads it
}

__global__ void __launch_bounds__(NTHR, 2) gru_main(
    const float* x0, const float* __restrict__ hid,
    const float* __restrict__ WI0, const float* __restrict__ WH0,
    const float* __restrict__ WI1, const float* __restrict__ WH1,
    const float* __restrict__ BC0, const float* __restrict__ BC1,
    float* __restrict__ hA, float* __restrict__ hB, float* __restrict__ gi,
    float* ret, float* __restrict__ outh, int* bar) {
    __shared__ __align__(16) float Wi[12 * KPW];   // 28,800 B
    __shared__ __align__(16) float Wh[12 * KPW];   // 28,800 B
    int* cnt = bar;            // own 64B line
    int* gen = bar + 16;       // 8 shards, 64B apart
    int bno = 0;
    gru_layer<0>(x0,  hid,         WI0, WH0, BC0, hA, hB, gi, ret, outh,         Wi, Wh, cnt, gen, bno);
    gru_layer<1>(ret, hid + B * H, WI1, WH1, BC1, hA, hB, gi, ret, outh + B * H, Wi, Wh, cnt, gen, bno);
}

extern "C" void kernel_launch(void* const* d_in, const int* in_sizes, int n_in,
                              void* d_out, int out_size, void* d_ws, size_t ws_size,
                              hipStream_t stream) {
    const float* x0   = (const float*)d_in[0];
    const float* hid  = (const float*)d_in[1];
    const float* Wih0 = (const float*)d_in[2];
    const float* Whh0 = (const float*)d_in[3];
    const float* bih0 = (const float*)d_in[4];
    const float* bhh0 = (const float*)d_in[5];
    const float* Wih1 = (const float*)d_in[6];
    const float* Whh1 = (const float*)d_in[7];
    const float* bih1 = (const float*)d_in[8];
    const float* bhh1 = (const float*)d_in[9];

    float* ws  = (float*)d_ws;
    float* WI0 = ws + WI0_OFF;
    float* WH0 = ws + WH0_OFF;
    float* WI1 = ws + WI1_OFF;
    float* WH1 = ws + WH1_OFF;
    float* BC0 = ws + BC0_OFF;
    float* BC1 = ws + BC1_OFF;
    float* hA  = ws + HA_OFF;
    float* hB  = ws + HB_OFF;
    float* gi  = ws + GI_OFF;
    int*   bar = (int*)(ws + BAR_OFF);

    float* ret  = (float*)d_out;
    float* outh = ret + (size_t)B * T * H;

    build_wp<<<(IN0 * G3 + 255) / 256, 256, 0, stream>>>(Wih0, WI0, IN0);
    build_wp<<<(H * G3 + 255) / 256, 256, 0, stream>>>(Whh0, WH0, H);
    build_wp<<<(H * G3 + 255) / 256, 256, 0, stream>>>(Wih1, WI1, H);
    build_wp<<<(H * G3 + 255) / 256, 256, 0, stream>>>(Whh1, WH1, H);
    build_bc<<<(H + 255) / 256, 256, 0, stream>>>(bih0, bhh0, bih1, bhh1, BC0, BC1);
    init_bar<<<1, 256, 0, stream>>>(bar);

    gru_main<<<dim3(NBLK), dim3(NTHR), 0, stream>>>(
        x0, hid, WI0, WH0, WI1, WH1, BC0, BC1, hA, hB, gi, ret, outh, bar);
}

// Round 4
// 23440.190 us; speedup vs baseline: 1.7090x; 1.0270x over previous
//
#include <hip/hip_runtime.h>

#define B    64
#define T    512
#define H    600
#define G3   1800
#define IN0  300
#define NBLK 150    // 4 j-columns per block (150*4 = 600)
#define NTHR 512    // (bp:32) x (jj:4) x (kh:4) -> 8 waves/CU
#define TCH  16     // timesteps per gi chunk
#define NCHUNK (T / TCH)   // 32
#define KP   672    // padded K for the scan (600 + 72 zeros); 672/4 slices are quad-aligned
#define KQ   (KP / 4)      // 168 floats per kh slice = 42 float4
#define KPWH 684    // Wh LDS row stride: 684%32=12, kh*168%32=8 -> the 16 unique
                    // (jj,kh) b128 bases land 2-per-stride-4 bank slot = 2-way = free
#define KPW0 312    // Wi LDS row stride L0 (312%32=24 -> 4 jj bases on banks {0,8,16,24})
#define KPW1 600    // Wi LDS row stride L1 (600%32=24, same spread)

// ---------------- ws layout (floats) ----------------
#define WI0_OFF 0
#define WI0_SZ  (IN0 * G3)
#define WH_SZ   (H * G3)
#define WH0_OFF (WI0_OFF + WI0_SZ)
#define WI1_OFF (WH0_OFF + WH_SZ)
#define WH1_OFF (WI1_OFF + WH_SZ)
#define BC0_OFF (WH1_OFF + WH_SZ)
#define BC1_OFF (BC0_OFF + H * 4)
#define HA_OFF  (BC1_OFF + H * 4)
#define HB_OFF  (HA_OFF + B * KP)          // padded h buffers [B][672]
#define GI_OFF  (HB_OFF + B * KP)
#define GI_SZ   (TCH * B * H * 4)          // gi4: [tl][b][j][4]
#define BAR_OFF (GI_OFF + GI_SZ)           // 256 ints: cnt shards at [s*16], gen at [128+s*16]

// ---------------- grid barrier v4: sharded RMW-poll, single-acquire ------------
// Arrival: RELEASE fetch_add on shard (blockIdx&7) -> ~19 serialized RMWs per
// L3 line, 8 lines in parallel (was 150 on one line). Detector: lanes 0..7 of
// block 0's wave 0 each RMW-poll one shard (one 8-address wave instruction per
// round), __all combine; lane<8 release-stores 8 gen shards. Pollers RMW their
// gen shard (RMW executes at L3: always fresh, NO cache invalidation). Exactly
// ONE ACQUIRE load per block per step does the L1/L2 invalidate before reading
// remote h. Monotone counts = ABA-free. Shard targets: 150 = 6*19 + 2*18.
__device__ __forceinline__ void grid_barrier(int* __restrict__ bar, int& bno) {
    ++bno;
    __syncthreads();
    if (blockIdx.x == 0) {
        if (threadIdx.x < 64) {
            if (threadIdx.x == 0)
                __hip_atomic_fetch_add(&bar[0], 1, __ATOMIC_RELEASE, __HIP_MEMORY_SCOPE_AGENT);
            const int s = threadIdx.x;
            const int tgt = (s < 8) ? bno * ((s < 6) ? 19 : 18) : 0;
            for (;;) {
                int v = (s < 8)
                    ? __hip_atomic_fetch_add(&bar[s * 16], 0, __ATOMIC_RELAXED, __HIP_MEMORY_SCOPE_AGENT)
                    : 0x7fffffff;
                if (__all(v >= tgt)) break;
                __builtin_amdgcn_s_sleep(1);
            }
            if (threadIdx.x < 8)
                __hip_atomic_store(&bar[128 + threadIdx.x * 16], bno, __ATOMIC_RELEASE, __HIP_MEMORY_SCOPE_AGENT);
            if (threadIdx.x == 0)
                (void)__hip_atomic_load(&bar[0], __ATOMIC_ACQUIRE, __HIP_MEMORY_SCOPE_AGENT);
        }
    } else {
        if (threadIdx.x == 0) {
            __hip_atomic_fetch_add(&bar[(blockIdx.x & 7) * 16], 1, __ATOMIC_RELEASE, __HIP_MEMORY_SCOPE_AGENT);
            int* g = &bar[128 + (blockIdx.x & 7) * 16];
            while (__hip_atomic_fetch_add(g, 0, __ATOMIC_RELAXED, __HIP_MEMORY_SCOPE_AGENT) < bno)
                __builtin_amdgcn_s_sleep(1);
            (void)__hip_atomic_load(&bar[0], __ATOMIC_ACQUIRE, __HIP_MEMORY_SCOPE_AGENT);
        }
    }
    __syncthreads();
}

__global__ void init_bar(int* bar) { if (threadIdx.x < 256) bar[threadIdx.x] = 0; }

// Pack W[(g*H+j)][k] -> dst[k][j*3+g]  (k-major, gate-interleaved columns)
__global__ void build_wp(const float* __restrict__ W, float* __restrict__ dst, int kdim) {
    int idx = blockIdx.x * blockDim.x + threadIdx.x;
    if (idx >= kdim * G3) return;
    int k = idx / G3;
    int c = idx - k * G3;
    int j = c / 3;
    int g = c - j * 3;
    dst[idx] = W[(size_t)(g * H + j) * kdim + k];
}

// BC[j] = (bih_r+bhh_r, bih_z+bhh_z, bih_n, bhh_n)
__global__ void build_bc(const float* __restrict__ bih0, const float* __restrict__ bhh0,
                         const float* __restrict__ bih1, const float* __restrict__ bhh1,
                         float* __restrict__ BC0, float* __restrict__ BC1) {
    int j = blockIdx.x * blockDim.x + threadIdx.x;
    if (j >= H) return;
    BC0[j * 4 + 0] = bih0[j] + bhh0[j];
    BC0[j * 4 + 1] = bih0[H + j] + bhh0[H + j];
    BC0[j * 4 + 2] = bih0[2 * H + j];
    BC0[j * 4 + 3] = bhh0[2 * H + j];
    BC1[j * 4 + 0] = bih1[j] + bhh1[j];
    BC1[j * 4 + 1] = bih1[H + j] + bhh1[H + j];
    BC1[j * 4 + 2] = bih1[2 * H + j];
    BC1[j * 4 + 3] = bhh1[2 * H + j];
}

// Dual-batch triple dot over N4 float4s: two global h streams (ping-pong
// double-buffered, CH float4 in flight each), shared LDS weight reads.
// Each weight quad feeds 24 FMAs (2 batches x 3 gates). Handles odd N4/CH.
template<int N4, int CH>
__device__ __forceinline__ void dot3x2(const float4* __restrict__ a0,
                                       const float4* __restrict__ a1,
                                       const float* wr, const float* wz, const float* wn,
                                       float& sr0, float& sz0, float& sn0,
                                       float& sr1, float& sz1, float& sn1) {
    constexpr int NCH = N4 / CH;
    static_assert(N4 % CH == 0, "chunking");
    float4 A0[CH], A1[CH], B0[CH], B1[CH];
    #pragma unroll
    for (int i = 0; i < CH; ++i) { A0[i] = a0[i]; A1[i] = a1[i]; }
    #pragma unroll 1
    for (int c = 0; c < NCH; c += 2) {
        if (c + 1 < NCH) {
            const float4* p0 = a0 + (c + 1) * CH;
            const float4* p1 = a1 + (c + 1) * CH;
            #pragma unroll
            for (int i = 0; i < CH; ++i) { B0[i] = p0[i]; B1[i] = p1[i]; }
        }
        #pragma unroll
        for (int i = 0; i < CH; ++i) {
            const int k = (c * CH + i) * 4;
            const float4 wR = *(const float4*)(wr + k);
            const float4 wZ = *(const float4*)(wz + k);
            const float4 wN = *(const float4*)(wn + k);
            float4 a = A0[i];
            sr0 += a.x * wR.x + a.y * wR.y + a.z * wR.z + a.w * wR.w;
            sz0 += a.x * wZ.x + a.y * wZ.y + a.z * wZ.z + a.w * wZ.w;
            sn0 += a.x * wN.x + a.y * wN.y + a.z * wN.z + a.w * wN.w;
            a = A1[i];
            sr1 += a.x * wR.x + a.y * wR.y + a.z * wR.z + a.w * wR.w;
            sz1 += a.x * wZ.x + a.y * wZ.y + a.z * wZ.z + a.w * wZ.w;
            sn1 += a.x * wN.x + a.y * wN.y + a.z * wN.z + a.w * wN.w;
        }
        if (c + 1 < NCH) {
            if (c + 2 < NCH) {
                const float4* p0 = a0 + (c + 2) * CH;
                const float4* p1 = a1 + (c + 2) * CH;
                #pragma unroll
                for (int i = 0; i < CH; ++i) { A0[i] = p0[i]; A1[i] = p1[i]; }
            }
            #pragma unroll
            for (int i = 0; i < CH; ++i) {
                const int k = ((c + 1) * CH + i) * 4;
                const float4 wR = *(const float4*)(wr + k);
                const float4 wZ = *(const float4*)(wz + k);
                const float4 wN = *(const float4*)(wn + k);
                float4 a = B0[i];
                sr0 += a.x * wR.x + a.y * wR.y + a.z * wR.z + a.w * wR.w;
                sz0 += a.x * wZ.x + a.y * wZ.y + a.z * wZ.z + a.w * wZ.w;
                sn0 += a.x * wN.x + a.y * wN.y + a.z * wN.z + a.w * wN.w;
                a = B1[i];
                sr1 += a.x * wR.x + a.y * wR.y + a.z * wR.z + a.w * wR.w;
                sz1 += a.x * wZ.x + a.y * wZ.y + a.z * wZ.z + a.w * wZ.w;
                sn1 += a.x * wN.x + a.y * wN.y + a.z * wN.z + a.w * wN.w;
            }
        }
    }
}

// Input-GEMM inner: 8 consecutive t-rows of one batch vs this thread's 3 gate
// columns. Weight LDS triple amortized over 96 FMAs; x ping-pong double-buffered.
template<int KIN>
__device__ __forceinline__ void gemm8(const float* xb,
                                      const float* wr, const float* wz, const float* wn,
                                      float* aR, float* aZ, float* aN) {
    constexpr int N4 = KIN / 4;
    float4 X[8], Y[8];
    #pragma unroll
    for (int i = 0; i < 8; ++i) X[i] = *(const float4*)(xb + (size_t)i * KIN);
    #pragma unroll 1
    for (int c = 0; c < N4; c += 2) {
        if (c + 1 < N4) {
            #pragma unroll
            for (int i = 0; i < 8; ++i) Y[i] = *(const float4*)(xb + (size_t)i * KIN + (c + 1) * 4);
        }
        {
            const int k = c * 4;
            const float4 wR = *(const float4*)(wr + k);
            const float4 wZ = *(const float4*)(wz + k);
            const float4 wN = *(const float4*)(wn + k);
            #pragma unroll
            for (int i = 0; i < 8; ++i) {
                const float4 a = X[i];
                aR[i] += a.x * wR.x + a.y * wR.y + a.z * wR.z + a.w * wR.w;
                aZ[i] += a.x * wZ.x + a.y * wZ.y + a.z * wZ.z + a.w * wZ.w;
                aN[i] += a.x * wN.x + a.y * wN.y + a.z * wN.z + a.w * wN.w;
            }
        }
        if (c + 1 < N4) {
            if (c + 2 < N4) {
                #pragma unroll
                for (int i = 0; i < 8; ++i) X[i] = *(const float4*)(xb + (size_t)i * KIN + (c + 2) * 4);
            }
            const int k = (c + 1) * 4;
            const float4 wR = *(const float4*)(wr + k);
            const float4 wZ = *(const float4*)(wz + k);
            const float4 wN = *(const float4*)(wn + k);
            #pragma unroll
            for (int i = 0; i < 8; ++i) {
                const float4 a = Y[i];
                aR[i] += a.x * wR.x + a.y * wR.y + a.z * wR.z + a.w * wR.w;
                aZ[i] += a.x * wZ.x + a.y * wZ.y + a.z * wZ.z + a.w * wZ.w;
                aN[i] += a.x * wN.x + a.y * wN.y + a.z * wN.z + a.w * wN.w;
            }
        }
    }
}

// x and ret may alias (layer 1) -> both non-restrict.
template<int LAYER>
__device__ void gru_layer(const float* x, const float* __restrict__ hid,
                          const float* __restrict__ WIp, const float* __restrict__ WHp,
                          const float* __restrict__ BC,
                          float* __restrict__ hA, float* __restrict__ hB,
                          float* __restrict__ gi, float* ret, float* __restrict__ outh,
                          float* Wi, float* Wh, int* bar, int& bno) {
    constexpr int KIN  = LAYER ? H : IN0;
    constexpr int KPWI = LAYER ? KPW1 : KPW0;
    const int tid = threadIdx.x;
    const int jj = tid & 3;            // j column within block
    const int kh = (tid >> 2) & 3;     // K-quarter (scan); (batch-half, octet) in GEMM
    const int bp = tid >> 4;           // batch pair 0..31: batches {bp, bp+32}
    const int b0 = bp, b1 = bp + 32;
    const int j  = blockIdx.x * 4 + jj;
    const int wcol0 = blockIdx.x * 12;
    const int bg  = bp + (kh >> 1) * 32;   // GEMM batch 0..63
    const int oct = kh & 1;                // GEMM t-row octet

    // Stage this block's 12 W_ih and 12 zero-padded W_hh gate-columns into LDS.
    for (int idx = tid; idx < 12 * KIN; idx += NTHR) {
        int k = idx / 12, c = idx - k * 12;
        Wi[c * KPWI + k] = WIp[(size_t)k * G3 + wcol0 + c];
    }
    for (int idx = tid; idx < 12 * KP; idx += NTHR) {
        int k = idx / 12, c = idx - k * 12;
        Wh[c * KPWH + k] = (k < H) ? WHp[(size_t)k * G3 + wcol0 + c] : 0.f;
    }
    // h buffers, padded layout [B][KP]; pads MUST be finite (they hit zero weights).
    for (int idx = blockIdx.x * NTHR + tid; idx < B * KP; idx += NBLK * NTHR) {
        int bb = idx / KP, col = idx - bb * KP;
        float v = (col < H) ? hid[bb * H + col] : 0.f;
        __builtin_nontemporal_store(v, &hA[idx]);
        __builtin_nontemporal_store(v, &hB[idx]);
    }
    grid_barrier(bar, bno);   // covers LDS staging + h init

    const float4 bc = *(const float4*)(BC + j * 4);
    const float* wrI = &Wi[(jj * 3 + 0) * KPWI];
    const float* wzI = &Wi[(jj * 3 + 1) * KPWI];
    const float* wnI = &Wi[(jj * 3 + 2) * KPWI];
    const float* wrH = &Wh[(jj * 3 + 0) * KPWH + kh * KQ];
    const float* wzH = &Wh[(jj * 3 + 1) * KPWH + kh * KQ];
    const float* wnH = &Wh[(jj * 3 + 2) * KPWH + kh * KQ];

    float hv0 = hid[b0 * H + j];       // recurrent state (kh==0 lanes maintain)
    float hv1 = hid[b1 * H + j];
    float hold0 = 0.f, hold1 = 0.f;    // LAYER 1 lag-write holds

    float* hc = hA;
    float* hn = hB;

    #pragma unroll 1
    for (int ch = 0; ch < NCHUNK; ++ch) {
        const int t0 = ch * TCH;

        // ---- gi GEMM phase: all 512 threads; batch bg, rows t0+oct*8..+7 ----
        {
            float aR[8], aZ[8], aN[8];
            #pragma unroll
            for (int i = 0; i < 8; ++i) { aR[i] = 0.f; aZ[i] = 0.f; aN[i] = 0.f; }
            const float* xb = x + ((size_t)bg * T + t0 + oct * 8) * KIN;
            gemm8<KIN>(xb, wrI, wzI, wnI, aR, aZ, aN);
            #pragma unroll
            for (int i = 0; i < 8; ++i) {
                float4 o;
                o.x = aR[i] + bc.x;   // r pre-activation + both r biases
                o.y = aZ[i] + bc.y;   // z pre-activation + both z biases
                o.z = aN[i] + bc.z;   // n x-part + bih_n
                o.w = bc.w;           // bhh_n (added inside r*(.) in scan)
                *(float4*)(gi + ((size_t)((oct * 8 + i) * B + bg) * H + j) * 4) = o;
            }
        }
        // gi for (b, j) written and read by the SAME block -> block barrier only.
        __syncthreads();

        // ---- scan: 16 sequential steps; thread = 2 batches x K-quarter ----
        #pragma unroll 1
        for (int tl = 0; tl < TCH; ++tl) {
            const int t = t0 + tl;
            float4 g40, g41;
            if (kh == 0) {
                g40 = *(const float4*)(gi + ((size_t)(tl * B + b0) * H + j) * 4);
                g41 = *(const float4*)(gi + ((size_t)(tl * B + b1) * H + j) * 4);
            }
            float sr0 = 0.f, sz0 = 0.f, sn0 = 0.f, sr1 = 0.f, sz1 = 0.f, sn1 = 0.f;
            dot3x2<KQ / 4, 6>((const float4*)(hc + (size_t)b0 * KP + kh * KQ),
                              (const float4*)(hc + (size_t)b1 * KP + kh * KQ),
                              wrH, wzH, wnH, sr0, sz0, sn0, sr1, sz1, sn1);
            // combine K-quarters: kh sits in lane bits 2-3 -> butterfly xor 4, 8
            sr0 += __shfl_xor(sr0, 4); sr0 += __shfl_xor(sr0, 8);
            sz0 += __shfl_xor(sz0, 4); sz0 += __shfl_xor(sz0, 8);
            sn0 += __shfl_xor(sn0, 4); sn0 += __shfl_xor(sn0, 8);
            sr1 += __shfl_xor(sr1, 4); sr1 += __shfl_xor(sr1, 8);
            sz1 += __shfl_xor(sz1, 4); sz1 += __shfl_xor(sz1, 8);
            sn1 += __shfl_xor(sn1, 4); sn1 += __shfl_xor(sn1, 8);
            if (kh == 0) {
                float r0 = 1.f / (1.f + __expf(-(sr0 + g40.x)));
                float z0 = 1.f / (1.f + __expf(-(sz0 + g40.y)));
                float n0 = tanhf(g40.z + r0 * (sn0 + g40.w));
                hv0 = (1.f - z0) * n0 + z0 * hv0;
                __builtin_nontemporal_store(hv0, &hn[(size_t)b0 * KP + j]);
                float r1 = 1.f / (1.f + __expf(-(sr1 + g41.x)));
                float z1 = 1.f / (1.f + __expf(-(sz1 + g41.y)));
                float n1 = tanhf(g41.z + r1 * (sn1 + g41.w));
                hv1 = (1.f - z1) * n1 + z1 * hv1;
                __builtin_nontemporal_store(hv1, &hn[(size_t)b1 * KP + j]);
                if (LAYER == 0) {
                    __builtin_nontemporal_store(hv0, &ret[((size_t)b0 * T + t) * H + j]);
                    __builtin_nontemporal_store(hv1, &ret[((size_t)b1 * T + t) * H + j]);
                } else {
                    // lag-write: row t-1 was GEMM-read >= one barrier+dot ago
                    if (t > 0) {
                        __builtin_nontemporal_store(hold0, &ret[((size_t)b0 * T + (t - 1)) * H + j]);
                        __builtin_nontemporal_store(hold1, &ret[((size_t)b1 * T + (t - 1)) * H + j]);
                    }
                    hold0 = hv0; hold1 = hv1;
                }
            }
            grid_barrier(bar, bno);   // h all-to-all exchange
            float* tmp = hc; hc = hn; hn = tmp;
        }
    }
    if (kh == 0) {
        if (LAYER == 1) {
            __builtin_nontemporal_store(hold0, &ret[((size_t)b0 * T + (T - 1)) * H + j]);
            __builtin_nontemporal_store(hold1, &ret[((size_t)b1 * T + (T - 1)) * H + j]);
        }
        __builtin_nontemporal_store(hv0, &outh[b0 * H + j]);
        __builtin_nontemporal_store(hv1, &outh[b1 * H + j]);
    }
    grid_barrier(bar, bno);   // ret complete before next layer's GEMM reads it
}

__global__ void __launch_bounds__(NTHR, 2) gru_main(
    const float* x0, const float* __restrict__ hid,
    const float* __restrict__ WI0, const float* __restrict__ WH0,
    const float* __restrict__ WI1, const float* __restrict__ WH1,
    const float* __restrict__ BC0, const float* __restrict__ BC1,
    float* __restrict__ hA, float* __restrict__ hB, float* __restrict__ gi,
    float* ret, float* __restrict__ outh, int* bar) {
    __shared__ __align__(16) float Wi[12 * KPW1];   // 28,800 B (L0 uses stride KPW0)
    __shared__ __align__(16) float Wh[12 * KPWH];   // 32,832 B -> total 61,632 B
    int bno = 0;
    gru_layer<0>(x0,  hid,         WI0, WH0, BC0, hA, hB, gi, ret, outh,         Wi, Wh, bar, bno);
    gru_layer<1>(ret, hid + B * H, WI1, WH1, BC1, hA, hB, gi, ret, outh + B * H, Wi, Wh, bar, bno);
}

extern "C" void kernel_launch(void* const* d_in, const int* in_sizes, int n_in,
                              void* d_out, int out_size, void* d_ws, size_t ws_size,
                              hipStream_t stream) {
    const float* x0   = (const float*)d_in[0];
    const float* hid  = (const float*)d_in[1];
    const float* Wih0 = (const float*)d_in[2];
    const float* Whh0 = (const float*)d_in[3];
    const float* bih0 = (const float*)d_in[4];
    const float* bhh0 = (const float*)d_in[5];
    const float* Wih1 = (const float*)d_in[6];
    const float* Whh1 = (const float*)d_in[7];
    const float* bih1 = (const float*)d_in[8];
    const float* bhh1 = (const float*)d_in[9];

    float* ws  = (float*)d_ws;
    float* WI0 = ws + WI0_OFF;
    float* WH0 = ws + WH0_OFF;
    float* WI1 = ws + WI1_OFF;
    float* WH1 = ws + WH1_OFF;
    float* BC0 = ws + BC0_OFF;
    float* BC1 = ws + BC1_OFF;
    float* hA  = ws + HA_OFF;
    float* hB  = ws + HB_OFF;
    float* gi  = ws + GI_OFF;
    int*   bar = (int*)(ws + BAR_OFF);

    float* ret  = (float*)d_out;
    float* outh = ret + (size_t)B * T * H;

    build_wp<<<(IN0 * G3 + 255) / 256, 256, 0, stream>>>(Wih0, WI0, IN0);
    build_wp<<<(H * G3 + 255) / 256, 256, 0, stream>>>(Whh0, WH0, H);
    build_wp<<<(H * G3 + 255) / 256, 256, 0, stream>>>(Wih1, WI1, H);
    build_wp<<<(H * G3 + 255) / 256, 256, 0, stream>>>(Whh1, WH1, H);
    build_bc<<<(H + 255) / 256, 256, 0, stream>>>(bih0, bhh0, bih1, bhh1, BC0, BC1);
    init_bar<<<1, 256, 0, stream>>>(bar);

    gru_main<<<dim3(NBLK), dim3(NTHR), 0, stream>>>(
        x0, hid, WI0, WH0, WI1, WH1, BC0, BC1, hA, hB, gi, ret, outh, bar);
}